// Round 6
// baseline (496.968 us; speedup 1.0000x reference)
//
#include <hip/hip_runtime.h>
#include <hip/hip_bf16.h>
#include <math.h>

// Problem constants (fixed by setup_inputs)
#define BB    4
#define NTOK  16384
#define CIN   128
#define COUT  256
#define HM    256
#define WM    256
#define NP    65536      // HM*WM original points per batch
#define HD    128
#define WD    128
#define HC    64
#define WC    64
#define NS    4096       // HC*WC
#define EPS   1e-6f
#define BNEPS 1e-5f

// CSR segment bases (concatenated target domains)
#define SEG_TOK  (BB * NP)                  // 262144
#define SEG_64   (SEG_TOK + BB * NTOK)      // 327680
#define NSEG     (SEG_64 + BB * NS)         // 344064 = 336 * 1024

typedef __attribute__((ext_vector_type(8))) short bfrag8;
typedef __attribute__((ext_vector_type(4))) float ffrag4;
typedef __attribute__((ext_vector_type(4))) float f32x4;
typedef __attribute__((ext_vector_type(4))) unsigned short u16x4;

// ---------------- workspace layout (floats) ----------------
// zeroed block first (one small memset), then non-zeroed scratch
static constexpr size_t BNSUM_OFF  = 0;                                   // 256
static constexpr size_t BNSQ_OFF   = BNSUM_OFF + 256;                     // 256
static constexpr size_t MAXW_OFF   = BNSQ_OFF + 256;                      // 4 (pad 256)
static constexpr size_t CNTS_OFF   = MAXW_OFF + 256;                      // NSEG ints
static constexpr size_t CURS_OFF   = CNTS_OFF + NSEG;                     // NSEG ints
static constexpr size_t ZERO_FLOATS = CURS_OFF + NSEG;
// non-zeroed:
static constexpr size_t YBUF_OFF   = (ZERO_FLOATS + 255) & ~(size_t)255;  // BB*HD*WD*COUT bf16 -> /2 floats
static constexpr size_t XMAPN_OFF  = YBUF_OFF + (size_t)BB * HD * WD * COUT / 2; // BB*NP*CIN bf16 -> /2
static constexpr size_t XBF_OFF    = XMAPN_OFF + (size_t)BB * NP * CIN / 2;  // BB*NTOK*CIN bf16 -> /2
static constexpr size_t TOKB_OFF   = XBF_OFF + (size_t)BB * NTOK * CIN / 2;  // BB*NTOK*COUT bf16 -> /2
static constexpr size_t WFRAG_OFF  = TOKB_OFF + (size_t)BB * NTOK * COUT / 2; // 9*4*16*512 bf16 -> /2
static constexpr size_t SFRAG_OFF  = WFRAG_OFF + (size_t)9 * 4 * 16 * 512 / 2; // 4*16*512 bf16 -> /2
static constexpr size_t WEXP_OFF   = SFRAG_OFF + (size_t)4 * 16 * 512 / 2;  // BB*NTOK
static constexpr size_t AWDT_OFF   = WEXP_OFF + (size_t)BB * NTOK;        // BB*NP
static constexpr size_t ABUF_OFF   = AWDT_OFF + (size_t)BB * NP;          // 256
static constexpr size_t BBUF_OFF   = ABUF_OFF + 256;                      // 256
static constexpr size_t CWA_OFF    = BBUF_OFF + 256;                      // 256
static constexpr size_t C0_OFF     = CWA_OFF + 256;                       // 256
static constexpr size_t CELL256_OFF = C0_OFF + 256;                       // BB*NP ints
static constexpr size_t CELL64_OFF  = CELL256_OFF + (size_t)BB * NP;      // BB*NP ints
static constexpr size_t DEN1_OFF   = CELL64_OFF + (size_t)BB * NP;        // BB*NTOK
static constexpr size_t DEN2_OFF   = DEN1_OFF + (size_t)BB * NTOK;        // BB*NS
static constexpr size_t STARTS_OFF = DEN2_OFF + (size_t)BB * NS;          // NSEG ints
static constexpr size_t BLKSUM_OFF = STARTS_OFF + NSEG;                   // 512 ints
static constexpr size_t BLKEXCL_OFF = BLKSUM_OFF + 512;                   // 512 ints
static constexpr size_t PIDX_OFF   = BLKEXCL_OFF + 512;                   // 3*BB*NP ints
static constexpr size_t POFF_OFF   = PIDX_OFF + (size_t)3 * BB * NP;      // BB*NP int4
static constexpr size_t PW_OFF     = POFF_OFF + (size_t)4 * BB * NP;      // BB*NP float4

// ---------------- helpers ----------------

__device__ __forceinline__ unsigned short f2bf(float f) {
    unsigned int u = __float_as_uint(f);
    return (unsigned short)((u + 0x7FFFu + ((u >> 16) & 1u)) >> 16);
}
__device__ __forceinline__ float bf2f(unsigned short u) {
    return __uint_as_float((unsigned int)u << 16);
}
// uint holding 2 packed bf16 -> floats
#define BFLO(u) __uint_as_float((u) << 16)
#define BFHI(u) __uint_as_float((u) & 0xffff0000u)

// non-temporal vector stores (streaming outputs -> don't pollute L2)
__device__ __forceinline__ void nts4(float* p, float a, float b, float c, float d) {
    f32x4 v = {a, b, c, d};
    __builtin_nontemporal_store(v, (f32x4*)p);
}
__device__ __forceinline__ void nts4f(float* p, float4 v) {
    nts4(p, v.x, v.y, v.z, v.w);
}
__device__ __forceinline__ void ntsu4(unsigned short* p, ushort4 v) {
    u16x4 t = {v.x, v.y, v.z, v.w};
    __builtin_nontemporal_store(t, (u16x4*)p);
}

// ---------------- kernels ----------------

// grid cell indices for both grids (RNE via rintf) + per-point bilinear record
// (4 corner offsets into HD*WD, 4 weights pre-multiplied by agg_weight)
__global__ void k_prep(const float* __restrict__ loc, const float* __restrict__ aggw,
                       int* __restrict__ cell256, int* __restrict__ cell64,
                       int4* __restrict__ poff, float4* __restrict__ pw) {
    int i = blockIdx.x * 256 + threadIdx.x;   // over BB*NP
    float lx = fminf(fmaxf(loc[2 * (size_t)i], -1.f), 1.f);
    float ly = fminf(fmaxf(loc[2 * (size_t)i + 1], -1.f), 1.f);
    int px = (int)rintf(0.5f * (lx + 1.f) * WM - 0.5f);
    px = min(max(px, 0), WM - 1);
    int py = (int)rintf(0.5f * (ly + 1.f) * HM - 0.5f);
    py = min(max(py, 0), HM - 1);
    cell256[i] = py * WM + px;
    int qx = (int)rintf(0.5f * (lx + 1.f) * WC - 0.5f);
    qx = min(max(qx, 0), WC - 1);
    int qy = (int)rintf(0.5f * (ly + 1.f) * HC - 0.5f);
    qy = min(max(qy, 0), HC - 1);
    cell64[i] = qy * WC + qx;
    // bilinear record on HD x WD (for map2token gather)
    float fx = fminf(fmaxf(0.5f * (lx + 1.f) * WD - 0.5f, 0.f), (float)(WD - 1));
    float fy = fminf(fmaxf(0.5f * (ly + 1.f) * HD - 0.5f, 0.f), (float)(HD - 1));
    float x0f = floorf(fx), y0f = floorf(fy);
    float wx = fx - x0f, wy = fy - y0f;
    int x0 = (int)x0f, y0 = (int)y0f;
    int x1 = min(x0 + 1, WD - 1), y1 = min(y0 + 1, HD - 1);
    int4 o;
    o.x = y0 * WD + x0; o.y = y0 * WD + x1;
    o.z = y1 * WD + x0; o.w = y1 * WD + x1;
    poff[i] = o;
    float aw = aggw[i];
    float4 w;
    w.x = (1.f - wx) * (1.f - wy) * aw;
    w.y = wx * (1.f - wy) * aw;
    w.z = (1.f - wx) * wy * aw;
    w.w = wx * wy * aw;
    pw[i] = w;
}

// cast x to bf16 once (random-gather source for k_gather_map)
__global__ void k_xcast(const float* __restrict__ x, unsigned short* __restrict__ xbf) {
    size_t i = (size_t)blockIdx.x * 256 + threadIdx.x;  // float4 groups
    float4 v = ((const float4*)x)[i];
    ushort4 o;
    o.x = f2bf(v.x); o.y = f2bf(v.y); o.z = f2bf(v.z); o.w = f2bf(v.w);
    ((ushort4*)xbf)[i] = o;
}

// histogram of all three target domains (concatenated)
__global__ void k_hist(const int* __restrict__ cell256, const int* __restrict__ idx_agg,
                       const int* __restrict__ cell64, int* __restrict__ cnts) {
    int gp = blockIdx.x * 256 + threadIdx.x;  // over BB*NP
    int b = gp >> 16;
    atomicAdd(&cnts[b * NP + cell256[gp]], 1);
    atomicAdd(&cnts[SEG_TOK + b * NTOK + idx_agg[gp]], 1);
    atomicAdd(&cnts[SEG_64 + b * NS + cell64[gp]], 1);
}

// 2-level exclusive scan over NSEG = 336*1024 counters
__global__ __launch_bounds__(256) void k_scan1(const int* __restrict__ cnts,
                                               int* __restrict__ starts,
                                               int* __restrict__ blksum) {
    int t = threadIdx.x;
    int base = blockIdx.x * 1024 + t * 4;
    int4 v = *(const int4*)(cnts + base);
    int tsum = v.x + v.y + v.z + v.w;
    __shared__ int s[256];
    s[t] = tsum;
    __syncthreads();
    for (int off = 1; off < 256; off <<= 1) {
        int add = (t >= off) ? s[t - off] : 0;
        __syncthreads();
        s[t] += add;
        __syncthreads();
    }
    int excl = s[t] - tsum;
    int4 o;
    o.x = excl; o.y = excl + v.x; o.z = o.y + v.y; o.w = o.z + v.z;
    *(int4*)(starts + base) = o;
    if (t == 255) blksum[blockIdx.x] = s[255];
}

__global__ __launch_bounds__(512) void k_scan2(const int* __restrict__ blksum,
                                               int* __restrict__ blkexcl) {
    int t = threadIdx.x;
    __shared__ int s[512];
    int v = (t < 336) ? blksum[t] : 0;
    s[t] = v;
    __syncthreads();
    for (int off = 1; off < 512; off <<= 1) {
        int add = (t >= off) ? s[t - off] : 0;
        __syncthreads();
        s[t] += add;
        __syncthreads();
    }
    if (t < 336) blkexcl[t] = s[t] - v;
}

// fill CSR pools: map stores resolved token id, tok stores point id, cell64 stores token id
__global__ void k_fill(const int* __restrict__ cell256, const int* __restrict__ idx_agg,
                       const int* __restrict__ cell64, const int* __restrict__ starts,
                       const int* __restrict__ blkexcl, int* __restrict__ curs,
                       int* __restrict__ pidx) {
    int gp = blockIdx.x * 256 + threadIdx.x;  // over BB*NP
    int b = gp >> 16;
    int ia = idx_agg[gp];
    int t1 = b * NP + cell256[gp];
    int p1 = starts[t1] + blkexcl[t1 >> 10] + atomicAdd(&curs[t1], 1);
    pidx[p1] = ia;
    int t2 = SEG_TOK + b * NTOK + ia;
    int p2 = starts[t2] + blkexcl[t2 >> 10] + atomicAdd(&curs[t2], 1);
    pidx[p2] = gp;
    int t3 = SEG_64 + b * NS + cell64[gp];
    int p3 = starts[t3] + blkexcl[t3 >> 10] + atomicAdd(&curs[t3], 1);
    pidx[p3] = ia;
}

// token2map as gather: per map cell, sum bf16 token rows, normalize, write bf16.
// Depth-1 software pipeline on pidx+row; non-temporal xmapn store keeps the
// xbf read set (4 MB/batch) resident in L2.
__global__ __launch_bounds__(256) void k_gather_map(const unsigned short* __restrict__ xbf,
                                                    const int* __restrict__ starts,
                                                    const int* __restrict__ blkexcl,
                                                    const int* __restrict__ cnts,
                                                    const int* __restrict__ pidx,
                                                    unsigned short* __restrict__ xmapn) {
    int tgt = blockIdx.x * 8 + (threadIdx.x >> 5);  // over BB*NP
    int lane = threadIdx.x & 31;                    // 32 lanes x 4ch = 128 ch
    int b = tgt >> 16;
    int start = starts[tgt] + blkexcl[tgt >> 10];
    int cnt = cnts[tgt];
    const unsigned short* xbb = xbf + (size_t)b * NTOK * CIN + lane * 4;
    float4 acc = make_float4(0.f, 0.f, 0.f, 0.f);
    if (cnt > 0) {
        int last = cnt - 1;
        int tk = pidx[start];
        ushort4 u = *(const ushort4*)(xbb + (size_t)tk * CIN);
        for (int j = 0; j < cnt; ++j) {
            int tkn = pidx[start + min(j + 1, last)];
            ushort4 un = *(const ushort4*)(xbb + (size_t)tkn * CIN);
            acc.x += bf2f(u.x); acc.y += bf2f(u.y);
            acc.z += bf2f(u.z); acc.w += bf2f(u.w);
            u = un;
        }
    }
    float inv = 1.0f / ((float)cnt + EPS);
    ushort4 o;
    o.x = f2bf(acc.x * inv);
    o.y = f2bf(acc.y * inv);
    o.z = f2bf(acc.z * inv);
    o.w = f2bf(acc.w * inv);
    ntsu4(xmapn + (size_t)tgt * CIN + lane * 4, o);
}

// pre-swizzle conv weights into MFMA 16x16x32 B-fragment lane layout
__global__ void k_wfrag(const float* __restrict__ cw, unsigned short* __restrict__ wfrag) {
    int i = blockIdx.x * 256 + threadIdx.x;  // over 9*4*16*512
    int j = i & 7;
    int lane = (i >> 3) & 63;
    int nt = (i >> 9) & 15;
    int kc = (i >> 13) & 3;
    int khw = i >> 15;
    int c = kc * 32 + ((lane >> 4) << 3) + j;
    int n = nt * 16 + (lane & 15);
    wfrag[i] = f2bf(cw[((size_t)khw * CIN + c) * COUT + n]);
}

// pre-swizzle skip weights (COUT x CIN, row-major) into same B-fragment layout
__global__ void k_sfrag(const float* __restrict__ sw, unsigned short* __restrict__ sfrag) {
    int i = blockIdx.x * 256 + threadIdx.x;  // over 4*16*512
    int j = i & 7;
    int lane = (i >> 3) & 63;
    int nt = (i >> 9) & 15;
    int kc = i >> 13;
    int c = kc * 32 + ((lane >> 4) << 3) + j;
    int n = nt * 16 + (lane & 15);
    sfrag[i] = f2bf(sw[(size_t)n * CIN + c]);
}

// 3x3 stride-2 pad-1 conv as implicit GEMM on bf16 MFMA 16x16x32; bf16 output.
// B-fragment (wfrag, L2-resident) register double-buffer: prefetch step s+1's
// 4 fragments while step s's 16 MFMAs run -> ~200cy L2 latency fully hidden.
__global__ __launch_bounds__(256, 4) void k_convmf(const unsigned short* __restrict__ xmapn,
                                                   const unsigned short* __restrict__ wfrag,
                                                   const float* __restrict__ cb,
                                                   unsigned short* __restrict__ y) {
    int bz = blockIdx.x;
    int ow0 = (bz & 1) * 64;
    int oh = (bz >> 1) & (HD - 1);
    int b = bz >> 8;
    int tid = threadIdx.x;
    int w = tid >> 6, lane = tid & 63;
    int n0 = w * 64;

    __shared__ unsigned short s_even[65 * 136];
    __shared__ unsigned short s_odd[64 * 136];

    ffrag4 acc[4][4];
#pragma unroll
    for (int mt = 0; mt < 4; ++mt)
#pragma unroll
        for (int nt = 0; nt < 4; ++nt) {
            ffrag4 z = {0.f, 0.f, 0.f, 0.f};
            acc[mt][nt] = z;
        }

    int iw0 = 2 * ow0 - 1;
    int lm = lane & 15;
    int lq = lane >> 4;
    int cbase = lq << 3;
    const unsigned short* wbase = wfrag + (size_t)(w * 4) * 512 + lane * 8;

#define LOAD_BF(dst, KHW, KC)                                                   \
    {                                                                           \
        const unsigned short* wb =                                              \
            wbase + (size_t)(((KHW) * 4 + (KC)) * 16) * 512;                    \
        _Pragma("unroll")                                                       \
        for (int nt = 0; nt < 4; ++nt)                                          \
            dst[nt] = *(const bfrag8*)(const void*)(wb + (size_t)nt * 512);     \
    }

#define LOAD_AF(dst, KW, KC)                                                    \
    {                                                                           \
        int c = (KC) * 32 + cbase;                                              \
        _Pragma("unroll")                                                       \
        for (int mt = 0; mt < 4; ++mt) {                                        \
            int m = mt * 16 + lm;                                               \
            const unsigned short* src;                                          \
            if ((KW) == 1)      src = &s_odd[(size_t)m * 136 + c];              \
            else if ((KW) == 0) src = &s_even[(size_t)m * 136 + c];             \
            else                src = &s_even[(size_t)(m + 1) * 136 + c];       \
            dst[mt] = *(const bfrag8*)(const void*)src;                         \
        }                                                                       \
    }

#define DO_MFMA(afv, bfv)                                                       \
    _Pragma("unroll")                                                           \
    for (int nt = 0; nt < 4; ++nt)                                              \
        _Pragma("unroll")                                                       \
        for (int mt = 0; mt < 4; ++mt)                                          \
            acc[mt][nt] = __builtin_amdgcn_mfma_f32_16x16x32_bf16(              \
                afv[mt], bfv[nt], acc[mt][nt], 0, 0, 0);

#pragma unroll
    for (int kh = 0; kh < 3; ++kh) {
        int ih = 2 * oh - 1 + kh;
        __syncthreads();
        {
            const unsigned short* rowb =
                xmapn + ((size_t)b * NP + (size_t)ih * WM) * CIN;
            bool ihok = (ih >= 0 && ih < HM);
            for (int idx = tid; idx < 129 * 16; idx += 256) {
                int pix = idx >> 4;
                int c8 = (idx & 15) * 8;
                int iw = iw0 + pix;
                uint4 v = make_uint4(0u, 0u, 0u, 0u);
                if (ihok && iw >= 0 && iw < WM)
                    v = *(const uint4*)(rowb + (size_t)iw * CIN + c8);
                unsigned short* dst = (pix & 1)
                    ? &s_odd[(size_t)((pix - 1) >> 1) * 136 + c8]
                    : &s_even[(size_t)(pix >> 1) * 136 + c8];
                *(uint4*)dst = v;
            }
        }
        __syncthreads();

        bfrag8 af[4], bfA[4], bfB[4];
        LOAD_BF(bfA, kh * 3 + 0, 0)
        LOAD_AF(af, 0, 0) LOAD_BF(bfB, kh * 3 + 0, 1) DO_MFMA(af, bfA)
        LOAD_AF(af, 0, 1) LOAD_BF(bfA, kh * 3 + 0, 2) DO_MFMA(af, bfB)
        LOAD_AF(af, 0, 2) LOAD_BF(bfB, kh * 3 + 0, 3) DO_MFMA(af, bfA)
        LOAD_AF(af, 0, 3) LOAD_BF(bfA, kh * 3 + 1, 0) DO_MFMA(af, bfB)
        LOAD_AF(af, 1, 0) LOAD_BF(bfB, kh * 3 + 1, 1) DO_MFMA(af, bfA)
        LOAD_AF(af, 1, 1) LOAD_BF(bfA, kh * 3 + 1, 2) DO_MFMA(af, bfB)
        LOAD_AF(af, 1, 2) LOAD_BF(bfB, kh * 3 + 1, 3) DO_MFMA(af, bfA)
        LOAD_AF(af, 1, 3) LOAD_BF(bfA, kh * 3 + 2, 0) DO_MFMA(af, bfB)
        LOAD_AF(af, 2, 0) LOAD_BF(bfB, kh * 3 + 2, 1) DO_MFMA(af, bfA)
        LOAD_AF(af, 2, 1) LOAD_BF(bfA, kh * 3 + 2, 2) DO_MFMA(af, bfB)
        LOAD_AF(af, 2, 2) LOAD_BF(bfB, kh * 3 + 2, 3) DO_MFMA(af, bfA)
        LOAD_AF(af, 2, 3)                             DO_MFMA(af, bfB)
    }
#undef LOAD_BF
#undef LOAD_AF
#undef DO_MFMA

    unsigned short* yb = y + (((size_t)b * HD + oh) * WD + ow0) * COUT;
#pragma unroll
    for (int nt = 0; nt < 4; ++nt) {
        int n = n0 + nt * 16 + lm;
        float bias = cb[n];
#pragma unroll
        for (int mt = 0; mt < 4; ++mt) {
#pragma unroll
            for (int r = 0; r < 4; ++r) {
                int m = mt * 16 + lq * 4 + r;
                yb[(size_t)m * COUT + n] = f2bf(acc[mt][nt][r] + bias);
            }
        }
    }
}

// map2token as gather: per token, precomputed bilinear records.
// half-wave parallel: lanes 0-31 handle point j, lanes 32-63 point j+1, 8 ch/lane.
// (round-4 body: records pipelined one pair ahead, corner loads NOT pipelined —
// the deeper pipeline regressed in round 5: occupancy 66->52, hbm 4.0->3.78)
#define ACC8(U, W)                                            \
    num[0] = fmaf(BFLO(U.x), W, num[0]);                      \
    num[1] = fmaf(BFHI(U.x), W, num[1]);                      \
    num[2] = fmaf(BFLO(U.y), W, num[2]);                      \
    num[3] = fmaf(BFHI(U.y), W, num[3]);                      \
    num[4] = fmaf(BFLO(U.z), W, num[4]);                      \
    num[5] = fmaf(BFHI(U.z), W, num[5]);                      \
    num[6] = fmaf(BFLO(U.w), W, num[6]);                      \
    num[7] = fmaf(BFHI(U.w), W, num[7]);

__global__ __launch_bounds__(256) void k_gather_tok(const unsigned short* __restrict__ y,
                                                    const int4* __restrict__ poff,
                                                    const float4* __restrict__ pw,
                                                    const int* __restrict__ starts,
                                                    const int* __restrict__ blkexcl,
                                                    const int* __restrict__ cnts,
                                                    const int* __restrict__ pidx,
                                                    float* __restrict__ num_out,
                                                    float* __restrict__ den1) {
    int wv = threadIdx.x >> 6, lane = threadIdx.x & 63;
    int tl = blockIdx.x * 4 + wv;                        // over BB*NTOK
    int b = tl >> 14;
    int tgt = SEG_TOK + tl;
    int start = starts[tgt] + blkexcl[tgt >> 10];
    int cnt = cnts[tgt];
    int half = lane >> 5;
    int ch = (lane & 31) * 8;
    const unsigned short* ybase = y + (size_t)b * (HD * WD * COUT) + ch;
    float num[8];
#pragma unroll
    for (int k = 0; k < 8; ++k) num[k] = 0.f;
    float den = 0.f;
    if (cnt > 0) {
        int last = cnt - 1;
        int jm = half;
        int gp = pidx[start + min(jm, last)];
        int4 off = poff[gp];
        float4 w = pw[gp];
        if (jm > last) w = make_float4(0.f, 0.f, 0.f, 0.f);
        for (int j2 = 0; j2 < cnt; j2 += 2) {
            int4 offc = off;
            float4 wc = w;
            int jn = j2 + 2 + half;
            if (j2 + 2 < cnt) {
                int gpn = pidx[start + min(jn, last)];
                off = poff[gpn];
                w = pw[gpn];
                if (jn > last) w = make_float4(0.f, 0.f, 0.f, 0.f);
            }
            uint4 u00 = *(const uint4*)(ybase + (size_t)offc.x * COUT);
            uint4 u01 = *(const uint4*)(ybase + (size_t)offc.y * COUT);
            uint4 u10 = *(const uint4*)(ybase + (size_t)offc.z * COUT);
            uint4 u11 = *(const uint4*)(ybase + (size_t)offc.w * COUT);
            ACC8(u00, wc.x)
            ACC8(u01, wc.y)
            ACC8(u10, wc.z)
            ACC8(u11, wc.w)
            den += wc.x + wc.y + wc.z + wc.w;
        }
    }
#pragma unroll
    for (int k = 0; k < 8; ++k) num[k] += __shfl_xor(num[k], 32, 64);
    den += __shfl_xor(den, 32, 64);
    if (half == 0) {
        float* o = num_out + (size_t)tl * COUT + ch;
        nts4(o, num[0], num[1], num[2], num[3]);
        nts4(o + 4, num[4], num[5], num[6], num[7]);
        if (lane == 0) den1[tl] = den;
    }
}

// tok = num/(den1+eps) + x @ skip_w^T via MFMA (in place over out_x region)
// Epilogue: acc is transposed through LDS in 4 chunks of 16 rows so the
// global RMW over tok becomes coalesced float4 loads/stores with high MLP.
// BN sum/sumsq accumulate in registers over the transposed view.
__global__ __launch_bounds__(256) void k_tokmf(const unsigned short* __restrict__ xbf,
                                               const unsigned short* __restrict__ sfrag,
                                               const float* __restrict__ den1,
                                               float* __restrict__ tok,
                                               float* __restrict__ bnsum,
                                               float* __restrict__ bnsq) {
    int t0 = blockIdx.x * 64;   // grid = BB*NTOK/64
    int tid = threadIdx.x;
    int w = tid >> 6, lane = tid & 63;
    int n0 = w * 64;
    int lm = lane & 15, lq = lane >> 4;

    // LDS reused: x-tile (bf16 [64][136] = 17408 B) then num chunks (f32 [16][324] = 20736 B)
    __shared__ __align__(16) unsigned char smem[16 * 324 * 4];
    unsigned short* s_x = (unsigned short*)smem;
    float* s_n = (float*)smem;

    const unsigned short* xb = xbf + (size_t)t0 * CIN;
    for (int idx = tid; idx < 64 * 16; idx += 256) {
        int row = idx >> 4, c8 = (idx & 15) * 8;
        *(uint4*)&s_x[(size_t)row * 136 + c8] = *(const uint4*)(xb + (size_t)row * CIN + c8);
    }
    __syncthreads();

    ffrag4 acc[4][4];
#pragma unroll
    for (int mt = 0; mt < 4; ++mt)
#pragma unroll
        for (int nt = 0; nt < 4; ++nt) {
            ffrag4 z = {0.f, 0.f, 0.f, 0.f};
            acc[mt][nt] = z;
        }

#pragma unroll
    for (int kc = 0; kc < 4; ++kc) {
        int c = kc * 32 + lq * 8;
        bfrag8 af[4];
#pragma unroll
        for (int mt = 0; mt < 4; ++mt)
            af[mt] = *(const bfrag8*)(const void*)&s_x[(size_t)(mt * 16 + lm) * 136 + c];
        const unsigned short* sb = sfrag + ((size_t)(kc * 16) + w * 4) * 512 + lane * 8;
#pragma unroll
        for (int nt = 0; nt < 4; ++nt) {
            bfrag8 bf = *(const bfrag8*)(const void*)(sb + (size_t)nt * 512);
#pragma unroll
            for (int mt = 0; mt < 4; ++mt)
                acc[mt][nt] = __builtin_amdgcn_mfma_f32_16x16x32_bf16(
                    af[mt], bf, acc[mt][nt], 0, 0, 0);
        }
    }

    // ---- transpose epilogue ----
    int row_r = tid >> 4;
    int cb = tid & 15;
    float bs[16], bq[16];
#pragma unroll
    for (int k = 0; k < 16; ++k) { bs[k] = 0.f; bq[k] = 0.f; }

#pragma unroll
    for (int chunk = 0; chunk < 4; ++chunk) {
        __syncthreads();
#pragma unroll
        for (int nt = 0; nt < 4; ++nt) {
            int cbw = (w * 4 + nt) * 20;
#pragma unroll
            for (int r = 0; r < 4; ++r)
                s_n[(lq * 4 + r) * 324 + cbw + lm] = acc[chunk][nt][r];
        }
        __syncthreads();
        int tkn = t0 + chunk * 16 + row_r;
        float inv = 1.f / (den1[tkn] + EPS);
        float* tp = tok + (size_t)tkn * COUT + cb * 16;
        const float* np = s_n + row_r * 324 + cb * 20;
        float4 g0 = ((const float4*)tp)[0];
        float4 g1 = ((const float4*)tp)[1];
        float4 g2 = ((const float4*)tp)[2];
        float4 g3 = ((const float4*)tp)[3];
        float4 l0 = ((const float4*)np)[0];
        float4 l1 = ((const float4*)np)[1];
        float4 l2 = ((const float4*)np)[2];
        float4 l3 = ((const float4*)np)[3];
#define RMW4(G, L, K)                                                       \
        {                                                                   \
            float v0 = fmaf(G.x, inv, L.x), v1 = fmaf(G.y, inv, L.y);       \
            float v2 = fmaf(G.z, inv, L.z), v3 = fmaf(G.w, inv, L.w);       \
            G.x = v0; G.y = v1; G.z = v2; G.w = v3;                         \
            bs[K+0] += v0; bq[K+0] = fmaf(v0, v0, bq[K+0]);                 \
            bs[K+1] += v1; bq[K+1] = fmaf(v1, v1, bq[K+1]);                 \
            bs[K+2] += v2; bq[K+2] = fmaf(v2, v2, bq[K+2]);                 \
            bs[K+3] += v3; bq[K+3] = fmaf(v3, v3, bq[K+3]);                 \
        }
        RMW4(g0, l0, 0)
        RMW4(g1, l1, 4)
        RMW4(g2, l2, 8)
        RMW4(g3, l3, 12)
#undef RMW4
        ((float4*)tp)[0] = g0;
        ((float4*)tp)[1] = g1;
        ((float4*)tp)[2] = g2;
        ((float4*)tp)[3] = g3;
    }

    // ---- BN reduction ----
#pragma unroll
    for (int k = 0; k < 16; ++k) {
        bs[k] += __shfl_xor(bs[k], 16, 64);
        bs[k] += __shfl_xor(bs[k], 32, 64);
        bq[k] += __shfl_xor(bq[k], 16, 64);
        bq[k] += __shfl_xor(bq[k], 32, 64);
    }
    __syncthreads();
    if (lq == 0) {
#pragma unroll
        for (int k = 0; k < 16; ++k) {
            s_n[w * 512 + lm * 16 + k] = bs[k];
            s_n[w * 512 + 256 + lm * 16 + k] = bq[k];
        }
    }
    __syncthreads();
    {
        int c = tid;
        float ts = s_n[c] + s_n[512 + c] + s_n[1024 + c] + s_n[1536 + c];
        float tq = s_n[256 + c] + s_n[768 + c] + s_n[1280 + c] + s_n[1792 + c];
        atomicAdd(bnsum + c, ts);
        atomicAdd(bnsq + c, tq);
    }
}

// per-channel BN affine: a=gamma/sqrt(var+eps), bb=beta-mu*a; fold conf head
__global__ void k_bnparams(const float* __restrict__ bnsum, const float* __restrict__ bnsq,
                           const float* __restrict__ gamma, const float* __restrict__ beta,
                           const float* __restrict__ confw, const float* __restrict__ confb,
                           float* __restrict__ abuf, float* __restrict__ bbuf,
                           float* __restrict__ cwa, float* __restrict__ c0) {
    int k = threadIdx.x;
    const float cntv = (float)(BB * NTOK);
    float mu = bnsum[k] / cntv;
    float var = bnsq[k] / cntv - mu * mu;
    float a = gamma[k] * rsqrtf(var + BNEPS);
    float bbv = beta[k] - mu * a;
    abuf[k] = a;
    bbuf[k] = bbv;
    float cw = confw[k];
    cwa[k] = a * cw;
    __shared__ float red[256];
    red[k] = bbv * cw;
    __syncthreads();
    for (int s = 128; s > 0; s >>= 1) {
        if (k < s) red[k] += red[k + s];
        __syncthreads();
    }
    if (k == 0) c0[0] = red[0] + confb[0];
}

// conf = dot(tok, cwa) + c0; emit tokn bf16 (tokb), exp(conf) (wexp),
// and fused relu(tokn) write-back into tok (non-temporal: final output)
__global__ void k_conf(float* __restrict__ tok, const float* __restrict__ cwa,
                       const float* __restrict__ c0v, const float* __restrict__ abuf,
                       const float* __restrict__ bbuf, float* __restrict__ conf_out,
                       unsigned short* __restrict__ tokb, float* __restrict__ wexp) {
    int tid = threadIdx.x;
    int tkn = blockIdx.x * 16 + (tid >> 4);
    int kc = (tid & 15) * 16;
    float* row = tok + (size_t)tkn * COUT + kc;
    unsigned short* tb = tokb + (size_t)tkn * COUT + kc;
    float s = 0.f;
#pragma unroll
    for (int i = 0; i < 16; i += 4) {
        float4 v = *(const float4*)(row + i);
        float4 w = *(const float4*)(cwa + kc + i);
        float4 a = *(const float4*)(abuf + kc + i);
        float4 bb = *(const float4*)(bbuf + kc + i);
        s += v.x * w.x + v.y * w.y + v.z * w.z + v.w * w.w;
        float t0 = fmaf(a.x, v.x, bb.x);
        float t1 = fmaf(a.y, v.y, bb.y);
        float t2 = fmaf(a.z, v.z, bb.z);
        float t3 = fmaf(a.w, v.w, bb.w);
        ushort4 o;
        o.x = f2bf(t0); o.y = f2bf(t1); o.z = f2bf(t2); o.w = f2bf(t3);
        *(ushort4*)(tb + i) = o;
        nts4(row + i, fmaxf(t0, 0.f), fmaxf(t1, 0.f), fmaxf(t2, 0.f), fmaxf(t3, 0.f));
    }
    for (int off = 8; off > 0; off >>= 1) s += __shfl_down(s, off, 16);
    if ((tid & 15) == 0) {
        float cv = s + c0v[0];
        conf_out[tkn] = cv;
        wexp[tkn] = expf(cv);
    }
}

// cluster as gather over bf16 tokn rows + precomputed exp weights; fused relu epilogue.
// half-wave parallel + depth-1 row pipeline; non-temporal xdown store (final output).
__global__ __launch_bounds__(256) void k_gather_cluster(const unsigned short* __restrict__ tokb,
                                                        const float* __restrict__ wexp,
                                                        const int* __restrict__ starts,
                                                        const int* __restrict__ blkexcl,
                                                        const int* __restrict__ cnts,
                                                        const int* __restrict__ pidx,
                                                        float* __restrict__ xdown,
                                                        float* __restrict__ den2) {
    int wv = threadIdx.x >> 6, lane = threadIdx.x & 63;
    int tl = blockIdx.x * 4 + wv;                        // over BB*NS
    int b = tl >> 12;
    int tgt = SEG_64 + tl;
    int start = starts[tgt] + blkexcl[tgt >> 10];
    int cnt = cnts[tgt];
    int half = lane >> 5;
    int ch = (lane & 31) * 8;
    const unsigned short* tb = tokb + (size_t)b * NTOK * COUT + ch;
    const float* we = wexp + (size_t)b * NTOK;
    float num[8];
#pragma unroll
    for (int k = 0; k < 8; ++k) num[k] = 0.f;
    float den = 0.f;
    if (cnt > 0) {
        int last = cnt - 1;
        int jc = half;
        int iac = pidx[start + min(jc, last)];
        float wc = (jc <= last) ? we[iac] : 0.f;
        int jn = 2 + half;
        int ian = pidx[start + min(jn, last)];
        float wn = (jn <= last) ? we[ian] : 0.f;
        const unsigned short* rpn = tb + (size_t)ian * COUT;
        uint4 u = *(const uint4*)(tb + (size_t)iac * COUT);
        for (int j2 = 0; j2 < cnt; j2 += 2) {
            uint4 un = *(const uint4*)rpn;         // next pair's row (dummy at tail)
            int j3 = j2 + 4 + half;
            int ia3 = pidx[start + min(j3, last)];
            float w3 = (j3 <= last) ? we[ia3] : 0.f;
            const unsigned short* rp3 = tb + (size_t)ia3 * COUT;
            ACC8(u, wc)
            den += wc;
            u = un; wc = wn;
            rpn = rp3; wn = w3;
        }
    }
#pragma unroll
    for (int k = 0; k < 8; ++k) num[k] += __shfl_xor(num[k], 32, 64);
    den += __shfl_xor(den, 32, 64);
    if (half == 0) {
        float inv = 1.f / (den + EPS);
        float* o = xdown + (size_t)tl * COUT + ch;
        nts4(o, fmaxf(num[0] * inv, 0.f), fmaxf(num[1] * inv, 0.f),
                fmaxf(num[2] * inv, 0.f), fmaxf(num[3] * inv, 0.f));
        nts4(o + 4, fmaxf(num[4] * inv, 0.f), fmaxf(num[5] * inv, 0.f),
                    fmaxf(num[6] * inv, 0.f), fmaxf(num[7] * inv, 0.f));
        if (lane == 0) den2[tl] = den;
    }
}

// agg_weight_down numerator + per-batch max (positive floats -> uint atomicMax)
__global__ void k_awd1(const float* __restrict__ wexp, const float* __restrict__ den2,
                       const int* __restrict__ idx_agg, const int* __restrict__ cell64,
                       const float* __restrict__ aggw, float* __restrict__ awdt,
                       float* __restrict__ idx_out_f, unsigned int* __restrict__ maxw) {
    int b = blockIdx.x >> 6;
    int chunk = blockIdx.x & 63;
    int base = b * NP + chunk * 1024;
    float lmax = 0.f;
    for (int t = threadIdx.x; t < 1024; t += 256) {
        int gp = base + t;
        int ia = idx_agg[gp];
        int cell = cell64[gp];
        float w = wexp[(size_t)b * NTOK + ia];
        float wt = w / (den2[(size_t)b * NS + cell] + EPS);
        float tv = aggw[gp] * wt;
        awdt[gp] = tv;
        __builtin_nontemporal_store((float)cell, idx_out_f + gp);
        lmax = fmaxf(lmax, tv);
    }
    __shared__ float red[256];
    red[threadIdx.x] = lmax;
    __syncthreads();
    for (int s = 128; s > 0; s >>= 1) {
        if (threadIdx.x < s) red[threadIdx.x] = fmaxf(red[threadIdx.x], red[threadIdx.x + s]);
        __syncthreads();
    }
    if (threadIdx.x == 0) atomicMax(maxw + b, __float_as_uint(red[0]));
}

__global__ void k_awd2(const float* __restrict__ awdt, const unsigned int* __restrict__ maxw,
                       float* __restrict__ awd_out) {
    int i = blockIdx.x * 256 + threadIdx.x;  // over BB*NP
    int b = i >> 16;
    __builtin_nontemporal_store(awdt[i] / __uint_as_float(maxw[b]), awd_out + i);
}

extern "C" void kernel_launch(void* const* d_in, const int* in_sizes, int n_in,
                              void* d_out, int out_size, void* d_ws, size_t ws_size,
                              hipStream_t stream) {
    const float* x        = (const float*)d_in[0];
    const float* loc      = (const float*)d_in[1];
    const int*   idx_agg  = (const int*)d_in[2];
    const float* aggw     = (const float*)d_in[3];
    const float* conv_w   = (const float*)d_in[4];
    const float* conv_b   = (const float*)d_in[5];
    const float* skip_w   = (const float*)d_in[6];
    const float* bn_gamma = (const float*)d_in[7];
    const float* bn_beta  = (const float*)d_in[8];
    const float* conf_w   = (const float*)d_in[9];
    const float* conf_b   = (const float*)d_in[10];

    float* ws      = (float*)d_ws;
    float* bnsum   = ws + BNSUM_OFF;
    float* bnsq    = ws + BNSQ_OFF;
    unsigned int* maxw = (unsigned int*)(ws + MAXW_OFF);
    int*   cnts    = (int*)(ws + CNTS_OFF);
    int*   curs    = (int*)(ws + CURS_OFF);
    unsigned short* ybuf  = (unsigned short*)(ws + YBUF_OFF);
    unsigned short* xmapn = (unsigned short*)(ws + XMAPN_OFF);
    unsigned short* xbf   = (unsigned short*)(ws + XBF_OFF);
    unsigned short* tokb  = (unsigned short*)(ws + TOKB_OFF);
    unsigned short* wfrag = (unsigned short*)(ws + WFRAG_OFF);
    unsigned short* sfrag = (unsigned short*)(ws + SFRAG_OFF);
    float* wexp    = ws + WEXP_OFF;
    float* awdt    = ws + AWDT_OFF;
    float* abuf    = ws + ABUF_OFF;
    float* bbuf    = ws + BBUF_OFF;
    float* cwa     = ws + CWA_OFF;
    float* c0      = ws + C0_OFF;
    int*   cell256 = (int*)(ws + CELL256_OFF);
    int*   cell64  = (int*)(ws + CELL64_OFF);
    float* den1    = ws + DEN1_OFF;
    float* den2    = ws + DEN2_OFF;
    int*   starts  = (int*)(ws + STARTS_OFF);
    int*   blksum  = (int*)(ws + BLKSUM_OFF);
    int*   blkexcl = (int*)(ws + BLKEXCL_OFF);
    int*   pidx    = (int*)(ws + PIDX_OFF);
    int4*  poff    = (int4*)(ws + POFF_OFF);
    float4* pwr    = (float4*)(ws + PW_OFF);

    float* out       = (float*)d_out;
    float* out_xdown = out;                                    // [4,4096,256]
    float* out_x     = out + (size_t)BB * NS * COUT;           // [4,16384,256] (num -> tok -> relu(tokn))
    float* out_conf  = out_x + (size_t)BB * NTOK * COUT;       // [4,16384,1]
    float* out_awd   = out_conf + (size_t)BB * NTOK;           // [4,65536,1]
    float* out_idx   = out_awd + (size_t)BB * NP;              // [4,65536] written as float

    // zero the small accumulator region (ws is poisoned 0xAA every call)
    hipMemsetAsync(d_ws, 0, ZERO_FLOATS * sizeof(float), stream);

    k_prep<<<BB * NP / 256, 256, 0, stream>>>(loc, aggw, cell256, cell64, poff, pwr);
    k_xcast<<<BB * NTOK * CIN / 4 / 256, 256, 0, stream>>>(x, xbf);
    k_wfrag<<<9 * 4 * 16 * 512 / 256, 256, 0, stream>>>(conv_w, wfrag);
    k_sfrag<<<4 * 16 * 512 / 256, 256, 0, stream>>>(skip_w, sfrag);
    k_hist<<<BB * NP / 256, 256, 0, stream>>>(cell256, idx_agg, cell64, cnts);
    k_scan1<<<NSEG / 1024, 256, 0, stream>>>(cnts, starts, blksum);
    k_scan2<<<1, 512, 0, stream>>>(blksum, blkexcl);
    k_fill<<<BB * NP / 256, 256, 0, stream>>>(cell256, idx_agg, cell64, starts,
                                              blkexcl, curs, pidx);
    k_gather_map<<<BB * NP / 8, 256, 0, stream>>>(xbf, starts, blkexcl, cnts, pidx, xmapn);
    k_convmf<<<BB * HD * 2, 256, 0, stream>>>(xmapn, wfrag, conv_b, ybuf);
    k_gather_tok<<<BB * NTOK / 4, 256, 0, stream>>>(ybuf, poff, pwr, starts, blkexcl,
                                                    cnts, pidx, out_x, den1);
    k_tokmf<<<BB * NTOK / 64, 256, 0, stream>>>(xbf, sfrag, den1, out_x, bnsum, bnsq);
    k_bnparams<<<1, 256, 0, stream>>>(bnsum, bnsq, bn_gamma, bn_beta, conf_w, conf_b,
                                      abuf, bbuf, cwa, c0);
    k_conf<<<BB * NTOK / 16, 256, 0, stream>>>(out_x, cwa, c0, abuf, bbuf,
                                               out_conf, tokb, wexp);
    k_gather_cluster<<<BB * NS / 4, 256, 0, stream>>>(tokb, wexp, starts, blkexcl,
                                                      cnts, pidx, out_xdown, den2);
    k_awd1<<<BB * 64, 256, 0, stream>>>(wexp, den2, idx_agg, cell64, aggw,
                                        awdt, out_idx, maxw);
    k_awd2<<<BB * NP / 256, 256, 0, stream>>>(awdt, maxw, out_awd);
}

// Round 7
// 476.865 us; speedup vs baseline: 1.0422x; 1.0422x over previous
//
#include <hip/hip_runtime.h>
#include <hip/hip_bf16.h>
#include <math.h>

// Problem constants (fixed by setup_inputs)
#define BB    4
#define NTOK  16384
#define CIN   128
#define COUT  256
#define HM    256
#define WM    256
#define NP    65536      // HM*WM original points per batch
#define HD    128
#define WD    128
#define HC    64
#define WC    64
#define NS    4096       // HC*WC
#define EPS   1e-6f
#define BNEPS 1e-5f

// CSR segment bases (concatenated target domains)
#define SEG_TOK  (BB * NP)                  // 262144
#define SEG_64   (SEG_TOK + BB * NTOK)      // 327680
#define NSEG     (SEG_64 + BB * NS)         // 344064 = 336 * 1024

typedef __attribute__((ext_vector_type(8))) short bfrag8;
typedef __attribute__((ext_vector_type(4))) float ffrag4;
typedef __attribute__((ext_vector_type(4))) float f32x4;

// ---------------- workspace layout (floats) ----------------
// zeroed block first (one small memset), then non-zeroed scratch
static constexpr size_t BNSUM_OFF  = 0;                                   // 256
static constexpr size_t BNSQ_OFF   = BNSUM_OFF + 256;                     // 256
static constexpr size_t MAXW_OFF   = BNSQ_OFF + 256;                      // 4 (pad 256)
static constexpr size_t CNTS_OFF   = MAXW_OFF + 256;                      // NSEG ints
static constexpr size_t CURS_OFF   = CNTS_OFF + NSEG;                     // NSEG ints
static constexpr size_t ZERO_FLOATS = CURS_OFF + NSEG;
// non-zeroed:
static constexpr size_t YBUF_OFF   = (ZERO_FLOATS + 255) & ~(size_t)255;  // BB*HD*WD*COUT bf16 -> /2 floats
static constexpr size_t XMAPN_OFF  = YBUF_OFF + (size_t)BB * HD * WD * COUT / 2; // BB*NP*CIN bf16 -> /2
static constexpr size_t XBF_OFF    = XMAPN_OFF + (size_t)BB * NP * CIN / 2;  // BB*NTOK*CIN bf16 -> /2
static constexpr size_t TOKB_OFF   = XBF_OFF + (size_t)BB * NTOK * CIN / 2;  // BB*NTOK*COUT bf16 -> /2
static constexpr size_t WFRAG_OFF  = TOKB_OFF + (size_t)BB * NTOK * COUT / 2; // 9*4*16*512 bf16 -> /2
static constexpr size_t SFRAG_OFF  = WFRAG_OFF + (size_t)9 * 4 * 16 * 512 / 2; // 4*16*512 bf16 -> /2
static constexpr size_t WEXP_OFF   = SFRAG_OFF + (size_t)4 * 16 * 512 / 2;  // BB*NTOK
static constexpr size_t AWDT_OFF   = WEXP_OFF + (size_t)BB * NTOK;        // BB*NP
static constexpr size_t ABUF_OFF   = AWDT_OFF + (size_t)BB * NP;          // 256
static constexpr size_t BBUF_OFF   = ABUF_OFF + 256;                      // 256
static constexpr size_t CWA_OFF    = BBUF_OFF + 256;                      // 256
static constexpr size_t C0_OFF     = CWA_OFF + 256;                       // 256
static constexpr size_t CELL256_OFF = C0_OFF + 256;                       // BB*NP ints
static constexpr size_t CELL64_OFF  = CELL256_OFF + (size_t)BB * NP;      // BB*NP ints
static constexpr size_t DEN1_OFF   = CELL64_OFF + (size_t)BB * NP;        // BB*NTOK
static constexpr size_t DEN2_OFF   = DEN1_OFF + (size_t)BB * NTOK;        // BB*NS
static constexpr size_t STARTS_OFF = DEN2_OFF + (size_t)BB * NS;          // NSEG ints
static constexpr size_t BLKSUM_OFF = STARTS_OFF + NSEG;                   // 512 ints
static constexpr size_t BLKEXCL_OFF = BLKSUM_OFF + 512;                   // 512 ints
static constexpr size_t PIDX_OFF   = BLKEXCL_OFF + 512;                   // 3*BB*NP ints
static constexpr size_t POFF_OFF   = PIDX_OFF + (size_t)3 * BB * NP;      // BB*NP int4
static constexpr size_t PW_OFF     = POFF_OFF + (size_t)4 * BB * NP;      // BB*NP float4

// ---------------- helpers ----------------

__device__ __forceinline__ unsigned short f2bf(float f) {
    unsigned int u = __float_as_uint(f);
    return (unsigned short)((u + 0x7FFFu + ((u >> 16) & 1u)) >> 16);
}
__device__ __forceinline__ float bf2f(unsigned short u) {
    return __uint_as_float((unsigned int)u << 16);
}
// uint holding 2 packed bf16 -> floats
#define BFLO(u) __uint_as_float((u) << 16)
#define BFHI(u) __uint_as_float((u) & 0xffff0000u)

// non-temporal vector store — ONLY for terminal outputs never re-read on
// device (nt bypasses L2+L3; round-6 showed using it on producer->consumer
// intermediates costs ~15 us by forcing consumers to HBM).
__device__ __forceinline__ void nts4(float* p, float a, float b, float c, float d) {
    f32x4 v = {a, b, c, d};
    __builtin_nontemporal_store(v, (f32x4*)p);
}

// ---------------- kernels ----------------

// grid cell indices for both grids (RNE via rintf) + per-point bilinear record
// (4 corner offsets into HD*WD, 4 weights pre-multiplied by agg_weight)
__global__ void k_prep(const float* __restrict__ loc, const float* __restrict__ aggw,
                       int* __restrict__ cell256, int* __restrict__ cell64,
                       int4* __restrict__ poff, float4* __restrict__ pw) {
    int i = blockIdx.x * 256 + threadIdx.x;   // over BB*NP
    float lx = fminf(fmaxf(loc[2 * (size_t)i], -1.f), 1.f);
    float ly = fminf(fmaxf(loc[2 * (size_t)i + 1], -1.f), 1.f);
    int px = (int)rintf(0.5f * (lx + 1.f) * WM - 0.5f);
    px = min(max(px, 0), WM - 1);
    int py = (int)rintf(0.5f * (ly + 1.f) * HM - 0.5f);
    py = min(max(py, 0), HM - 1);
    cell256[i] = py * WM + px;
    int qx = (int)rintf(0.5f * (lx + 1.f) * WC - 0.5f);
    qx = min(max(qx, 0), WC - 1);
    int qy = (int)rintf(0.5f * (ly + 1.f) * HC - 0.5f);
    qy = min(max(qy, 0), HC - 1);
    cell64[i] = qy * WC + qx;
    // bilinear record on HD x WD (for map2token gather)
    float fx = fminf(fmaxf(0.5f * (lx + 1.f) * WD - 0.5f, 0.f), (float)(WD - 1));
    float fy = fminf(fmaxf(0.5f * (ly + 1.f) * HD - 0.5f, 0.f), (float)(HD - 1));
    float x0f = floorf(fx), y0f = floorf(fy);
    float wx = fx - x0f, wy = fy - y0f;
    int x0 = (int)x0f, y0 = (int)y0f;
    int x1 = min(x0 + 1, WD - 1), y1 = min(y0 + 1, HD - 1);
    int4 o;
    o.x = y0 * WD + x0; o.y = y0 * WD + x1;
    o.z = y1 * WD + x0; o.w = y1 * WD + x1;
    poff[i] = o;
    float aw = aggw[i];
    float4 w;
    w.x = (1.f - wx) * (1.f - wy) * aw;
    w.y = wx * (1.f - wy) * aw;
    w.z = (1.f - wx) * wy * aw;
    w.w = wx * wy * aw;
    pw[i] = w;
}

// cast x to bf16 once (random-gather source for k_gather_map)
__global__ void k_xcast(const float* __restrict__ x, unsigned short* __restrict__ xbf) {
    size_t i = (size_t)blockIdx.x * 256 + threadIdx.x;  // float4 groups
    float4 v = ((const float4*)x)[i];
    ushort4 o;
    o.x = f2bf(v.x); o.y = f2bf(v.y); o.z = f2bf(v.z); o.w = f2bf(v.w);
    ((ushort4*)xbf)[i] = o;
}

// histogram of all three target domains (concatenated)
__global__ void k_hist(const int* __restrict__ cell256, const int* __restrict__ idx_agg,
                       const int* __restrict__ cell64, int* __restrict__ cnts) {
    int gp = blockIdx.x * 256 + threadIdx.x;  // over BB*NP
    int b = gp >> 16;
    atomicAdd(&cnts[b * NP + cell256[gp]], 1);
    atomicAdd(&cnts[SEG_TOK + b * NTOK + idx_agg[gp]], 1);
    atomicAdd(&cnts[SEG_64 + b * NS + cell64[gp]], 1);
}

// 2-level exclusive scan over NSEG = 336*1024 counters
__global__ __launch_bounds__(256) void k_scan1(const int* __restrict__ cnts,
                                               int* __restrict__ starts,
                                               int* __restrict__ blksum) {
    int t = threadIdx.x;
    int base = blockIdx.x * 1024 + t * 4;
    int4 v = *(const int4*)(cnts + base);
    int tsum = v.x + v.y + v.z + v.w;
    __shared__ int s[256];
    s[t] = tsum;
    __syncthreads();
    for (int off = 1; off < 256; off <<= 1) {
        int add = (t >= off) ? s[t - off] : 0;
        __syncthreads();
        s[t] += add;
        __syncthreads();
    }
    int excl = s[t] - tsum;
    int4 o;
    o.x = excl; o.y = excl + v.x; o.z = o.y + v.y; o.w = o.z + v.z;
    *(int4*)(starts + base) = o;
    if (t == 255) blksum[blockIdx.x] = s[255];
}

__global__ __launch_bounds__(512) void k_scan2(const int* __restrict__ blksum,
                                               int* __restrict__ blkexcl) {
    int t = threadIdx.x;
    __shared__ int s[512];
    int v = (t < 336) ? blksum[t] : 0;
    s[t] = v;
    __syncthreads();
    for (int off = 1; off < 512; off <<= 1) {
        int add = (t >= off) ? s[t - off] : 0;
        __syncthreads();
        s[t] += add;
        __syncthreads();
    }
    if (t < 336) blkexcl[t] = s[t] - v;
}

// fill CSR pools: map stores resolved token id, tok stores point id, cell64 stores token id
__global__ void k_fill(const int* __restrict__ cell256, const int* __restrict__ idx_agg,
                       const int* __restrict__ cell64, const int* __restrict__ starts,
                       const int* __restrict__ blkexcl, int* __restrict__ curs,
                       int* __restrict__ pidx) {
    int gp = blockIdx.x * 256 + threadIdx.x;  // over BB*NP
    int b = gp >> 16;
    int ia = idx_agg[gp];
    int t1 = b * NP + cell256[gp];
    int p1 = starts[t1] + blkexcl[t1 >> 10] + atomicAdd(&curs[t1], 1);
    pidx[p1] = ia;
    int t2 = SEG_TOK + b * NTOK + ia;
    int p2 = starts[t2] + blkexcl[t2 >> 10] + atomicAdd(&curs[t2], 1);
    pidx[p2] = gp;
    int t3 = SEG_64 + b * NS + cell64[gp];
    int p3 = starts[t3] + blkexcl[t3 >> 10] + atomicAdd(&curs[t3], 1);
    pidx[p3] = ia;
}

// token2map as gather: per map cell, sum bf16 token rows, normalize, write bf16.
// Depth-1 software pipeline on pidx+row. xmapn store is REGULAR (re-read by
// k_convmf — must stay L2/L3 resident; nt-store here cost ~3 us, round 6).
__global__ __launch_bounds__(256) void k_gather_map(const unsigned short* __restrict__ xbf,
                                                    const int* __restrict__ starts,
                                                    const int* __restrict__ blkexcl,
                                                    const int* __restrict__ cnts,
                                                    const int* __restrict__ pidx,
                                                    unsigned short* __restrict__ xmapn) {
    int tgt = blockIdx.x * 8 + (threadIdx.x >> 5);  // over BB*NP
    int lane = threadIdx.x & 31;                    // 32 lanes x 4ch = 128 ch
    int b = tgt >> 16;
    int start = starts[tgt] + blkexcl[tgt >> 10];
    int cnt = cnts[tgt];
    const unsigned short* xbb = xbf + (size_t)b * NTOK * CIN + lane * 4;
    float4 acc = make_float4(0.f, 0.f, 0.f, 0.f);
    if (cnt > 0) {
        int last = cnt - 1;
        int tk = pidx[start];
        ushort4 u = *(const ushort4*)(xbb + (size_t)tk * CIN);
        for (int j = 0; j < cnt; ++j) {
            int tkn = pidx[start + min(j + 1, last)];
            ushort4 un = *(const ushort4*)(xbb + (size_t)tkn * CIN);
            acc.x += bf2f(u.x); acc.y += bf2f(u.y);
            acc.z += bf2f(u.z); acc.w += bf2f(u.w);
            u = un;
        }
    }
    float inv = 1.0f / ((float)cnt + EPS);
    ushort4 o;
    o.x = f2bf(acc.x * inv);
    o.y = f2bf(acc.y * inv);
    o.z = f2bf(acc.z * inv);
    o.w = f2bf(acc.w * inv);
    *(ushort4*)(xmapn + (size_t)tgt * CIN + lane * 4) = o;
}

// pre-swizzle conv weights into MFMA 16x16x32 B-fragment lane layout
__global__ void k_wfrag(const float* __restrict__ cw, unsigned short* __restrict__ wfrag) {
    int i = blockIdx.x * 256 + threadIdx.x;  // over 9*4*16*512
    int j = i & 7;
    int lane = (i >> 3) & 63;
    int nt = (i >> 9) & 15;
    int kc = (i >> 13) & 3;
    int khw = i >> 15;
    int c = kc * 32 + ((lane >> 4) << 3) + j;
    int n = nt * 16 + (lane & 15);
    wfrag[i] = f2bf(cw[((size_t)khw * CIN + c) * COUT + n]);
}

// pre-swizzle skip weights (COUT x CIN, row-major) into same B-fragment layout
__global__ void k_sfrag(const float* __restrict__ sw, unsigned short* __restrict__ sfrag) {
    int i = blockIdx.x * 256 + threadIdx.x;  // over 4*16*512
    int j = i & 7;
    int lane = (i >> 3) & 63;
    int nt = (i >> 9) & 15;
    int kc = i >> 13;
    int c = kc * 32 + ((lane >> 4) << 3) + j;
    int n = nt * 16 + (lane & 15);
    sfrag[i] = f2bf(sw[(size_t)n * CIN + c]);
}

// 3x3 stride-2 pad-1 conv as implicit GEMM on bf16 MFMA 16x16x32; bf16 output.
// B-fragment (wfrag, L2-resident) register double-buffer: prefetch step s+1's
// 4 fragments while step s's 16 MFMAs run.
__global__ __launch_bounds__(256, 4) void k_convmf(const unsigned short* __restrict__ xmapn,
                                                   const unsigned short* __restrict__ wfrag,
                                                   const float* __restrict__ cb,
                                                   unsigned short* __restrict__ y) {
    int bz = blockIdx.x;
    int ow0 = (bz & 1) * 64;
    int oh = (bz >> 1) & (HD - 1);
    int b = bz >> 8;
    int tid = threadIdx.x;
    int w = tid >> 6, lane = tid & 63;
    int n0 = w * 64;

    __shared__ unsigned short s_even[65 * 136];
    __shared__ unsigned short s_odd[64 * 136];

    ffrag4 acc[4][4];
#pragma unroll
    for (int mt = 0; mt < 4; ++mt)
#pragma unroll
        for (int nt = 0; nt < 4; ++nt) {
            ffrag4 z = {0.f, 0.f, 0.f, 0.f};
            acc[mt][nt] = z;
        }

    int iw0 = 2 * ow0 - 1;
    int lm = lane & 15;
    int lq = lane >> 4;
    int cbase = lq << 3;
    const unsigned short* wbase = wfrag + (size_t)(w * 4) * 512 + lane * 8;

#define LOAD_BF(dst, KHW, KC)                                                   \
    {                                                                           \
        const unsigned short* wb =                                              \
            wbase + (size_t)(((KHW) * 4 + (KC)) * 16) * 512;                    \
        _Pragma("unroll")                                                       \
        for (int nt = 0; nt < 4; ++nt)                                          \
            dst[nt] = *(const bfrag8*)(const void*)(wb + (size_t)nt * 512);     \
    }

#define LOAD_AF(dst, KW, KC)                                                    \
    {                                                                           \
        int c = (KC) * 32 + cbase;                                              \
        _Pragma("unroll")                                                       \
        for (int mt = 0; mt < 4; ++mt) {                                        \
            int m = mt * 16 + lm;                                               \
            const unsigned short* src;                                          \
            if ((KW) == 1)      src = &s_odd[(size_t)m * 136 + c];              \
            else if ((KW) == 0) src = &s_even[(size_t)m * 136 + c];             \
            else                src = &s_even[(size_t)(m + 1) * 136 + c];       \
            dst[mt] = *(const bfrag8*)(const void*)src;                         \
        }                                                                       \
    }

#define DO_MFMA(afv, bfv)                                                       \
    _Pragma("unroll")                                                           \
    for (int nt = 0; nt < 4; ++nt)                                              \
        _Pragma("unroll")                                                       \
        for (int mt = 0; mt < 4; ++mt)                                          \
            acc[mt][nt] = __builtin_amdgcn_mfma_f32_16x16x32_bf16(              \
                afv[mt], bfv[nt], acc[mt][nt], 0, 0, 0);

#pragma unroll
    for (int kh = 0; kh < 3; ++kh) {
        int ih = 2 * oh - 1 + kh;
        __syncthreads();
        {
            const unsigned short* rowb =
                xmapn + ((size_t)b * NP + (size_t)ih * WM) * CIN;
            bool ihok = (ih >= 0 && ih < HM);
            for (int idx = tid; idx < 129 * 16; idx += 256) {
                int pix = idx >> 4;
                int c8 = (idx & 15) * 8;
                int iw = iw0 + pix;
                uint4 v = make_uint4(0u, 0u, 0u, 0u);
                if (ihok && iw >= 0 && iw < WM)
                    v = *(const uint4*)(rowb + (size_t)iw * CIN + c8);
                unsigned short* dst = (pix & 1)
                    ? &s_odd[(size_t)((pix - 1) >> 1) * 136 + c8]
                    : &s_even[(size_t)(pix >> 1) * 136 + c8];
                *(uint4*)dst = v;
            }
        }
        __syncthreads();

        bfrag8 af[4], bfA[4], bfB[4];
        LOAD_BF(bfA, kh * 3 + 0, 0)
        LOAD_AF(af, 0, 0) LOAD_BF(bfB, kh * 3 + 0, 1) DO_MFMA(af, bfA)
        LOAD_AF(af, 0, 1) LOAD_BF(bfA, kh * 3 + 0, 2) DO_MFMA(af, bfB)
        LOAD_AF(af, 0, 2) LOAD_BF(bfB, kh * 3 + 0, 3) DO_MFMA(af, bfA)
        LOAD_AF(af, 0, 3) LOAD_BF(bfA, kh * 3 + 1, 0) DO_MFMA(af, bfB)
        LOAD_AF(af, 1, 0) LOAD_BF(bfB, kh * 3 + 1, 1) DO_MFMA(af, bfA)
        LOAD_AF(af, 1, 1) LOAD_BF(bfA, kh * 3 + 1, 2) DO_MFMA(af, bfB)
        LOAD_AF(af, 1, 2) LOAD_BF(bfB, kh * 3 + 1, 3) DO_MFMA(af, bfA)
        LOAD_AF(af, 1, 3) LOAD_BF(bfA, kh * 3 + 2, 0) DO_MFMA(af, bfB)
        LOAD_AF(af, 2, 0) LOAD_BF(bfB, kh * 3 + 2, 1) DO_MFMA(af, bfA)
        LOAD_AF(af, 2, 1) LOAD_BF(bfA, kh * 3 + 2, 2) DO_MFMA(af, bfB)
        LOAD_AF(af, 2, 2) LOAD_BF(bfB, kh * 3 + 2, 3) DO_MFMA(af, bfA)
        LOAD_AF(af, 2, 3)                             DO_MFMA(af, bfB)
    }
#undef LOAD_BF
#undef LOAD_AF
#undef DO_MFMA

    unsigned short* yb = y + (((size_t)b * HD + oh) * WD + ow0) * COUT;
#pragma unroll
    for (int nt = 0; nt < 4; ++nt) {
        int n = n0 + nt * 16 + lm;
        float bias = cb[n];
#pragma unroll
        for (int mt = 0; mt < 4; ++mt) {
#pragma unroll
            for (int r = 0; r < 4; ++r) {
                int m = mt * 16 + lq * 4 + r;
                yb[(size_t)m * COUT + n] = f2bf(acc[mt][nt][r] + bias);
            }
        }
    }
}

// map2token as gather: per token, precomputed bilinear records.
// half-wave parallel: lanes 0-31 handle point j, lanes 32-63 point j+1, 8 ch/lane.
// (round-4 body: records pipelined one pair ahead; corner-load pipelining and
// nt num_out store both measured as regressions — rounds 5/6.)
#define ACC8(U, W)                                            \
    num[0] = fmaf(BFLO(U.x), W, num[0]);                      \
    num[1] = fmaf(BFHI(U.x), W, num[1]);                      \
    num[2] = fmaf(BFLO(U.y), W, num[2]);                      \
    num[3] = fmaf(BFHI(U.y), W, num[3]);                      \
    num[4] = fmaf(BFLO(U.z), W, num[4]);                      \
    num[5] = fmaf(BFHI(U.z), W, num[5]);                      \
    num[6] = fmaf(BFLO(U.w), W, num[6]);                      \
    num[7] = fmaf(BFHI(U.w), W, num[7]);

__global__ __launch_bounds__(256) void k_gather_tok(const unsigned short* __restrict__ y,
                                                    const int4* __restrict__ poff,
                                                    const float4* __restrict__ pw,
                                                    const int* __restrict__ starts,
                                                    const int* __restrict__ blkexcl,
                                                    const int* __restrict__ cnts,
                                                    const int* __restrict__ pidx,
                                                    float* __restrict__ num_out,
                                                    float* __restrict__ den1) {
    int wv = threadIdx.x >> 6, lane = threadIdx.x & 63;
    int tl = blockIdx.x * 4 + wv;                        // over BB*NTOK
    int b = tl >> 14;
    int tgt = SEG_TOK + tl;
    int start = starts[tgt] + blkexcl[tgt >> 10];
    int cnt = cnts[tgt];
    int half = lane >> 5;
    int ch = (lane & 31) * 8;
    const unsigned short* ybase = y + (size_t)b * (HD * WD * COUT) + ch;
    float num[8];
#pragma unroll
    for (int k = 0; k < 8; ++k) num[k] = 0.f;
    float den = 0.f;
    if (cnt > 0) {
        int last = cnt - 1;
        int jm = half;
        int gp = pidx[start + min(jm, last)];
        int4 off = poff[gp];
        float4 w = pw[gp];
        if (jm > last) w = make_float4(0.f, 0.f, 0.f, 0.f);
        for (int j2 = 0; j2 < cnt; j2 += 2) {
            int4 offc = off;
            float4 wc = w;
            int jn = j2 + 2 + half;
            if (j2 + 2 < cnt) {
                int gpn = pidx[start + min(jn, last)];
                off = poff[gpn];
                w = pw[gpn];
                if (jn > last) w = make_float4(0.f, 0.f, 0.f, 0.f);
            }
            uint4 u00 = *(const uint4*)(ybase + (size_t)offc.x * COUT);
            uint4 u01 = *(const uint4*)(ybase + (size_t)offc.y * COUT);
            uint4 u10 = *(const uint4*)(ybase + (size_t)offc.z * COUT);
            uint4 u11 = *(const uint4*)(ybase + (size_t)offc.w * COUT);
            ACC8(u00, wc.x)
            ACC8(u01, wc.y)
            ACC8(u10, wc.z)
            ACC8(u11, wc.w)
            den += wc.x + wc.y + wc.z + wc.w;
        }
    }
#pragma unroll
    for (int k = 0; k < 8; ++k) num[k] += __shfl_xor(num[k], 32, 64);
    den += __shfl_xor(den, 32, 64);
    if (half == 0) {
        float* o = num_out + (size_t)tl * COUT + ch;
        *(float4*)o = make_float4(num[0], num[1], num[2], num[3]);
        *(float4*)(o + 4) = make_float4(num[4], num[5], num[6], num[7]);
        if (lane == 0) den1[tl] = den;
    }
}

// tok = num/(den1+eps) + x @ skip_w^T via MFMA (in place over out_x region)
// Epilogue: acc is transposed through LDS in 4 chunks of 16 rows so the
// global RMW over tok becomes coalesced float4 loads/stores with high MLP.
// BN sum/sumsq accumulate in registers over the transposed view.
__global__ __launch_bounds__(256) void k_tokmf(const unsigned short* __restrict__ xbf,
                                               const unsigned short* __restrict__ sfrag,
                                               const float* __restrict__ den1,
                                               float* __restrict__ tok,
                                               float* __restrict__ bnsum,
                                               float* __restrict__ bnsq) {
    int t0 = blockIdx.x * 64;   // grid = BB*NTOK/64
    int tid = threadIdx.x;
    int w = tid >> 6, lane = tid & 63;
    int n0 = w * 64;
    int lm = lane & 15, lq = lane >> 4;

    // LDS reused: x-tile (bf16 [64][136] = 17408 B) then num chunks (f32 [16][324] = 20736 B)
    __shared__ __align__(16) unsigned char smem[16 * 324 * 4];
    unsigned short* s_x = (unsigned short*)smem;
    float* s_n = (float*)smem;

    const unsigned short* xb = xbf + (size_t)t0 * CIN;
    for (int idx = tid; idx < 64 * 16; idx += 256) {
        int row = idx >> 4, c8 = (idx & 15) * 8;
        *(uint4*)&s_x[(size_t)row * 136 + c8] = *(const uint4*)(xb + (size_t)row * CIN + c8);
    }
    __syncthreads();

    ffrag4 acc[4][4];
#pragma unroll
    for (int mt = 0; mt < 4; ++mt)
#pragma unroll
        for (int nt = 0; nt < 4; ++nt) {
            ffrag4 z = {0.f, 0.f, 0.f, 0.f};
            acc[mt][nt] = z;
        }

#pragma unroll
    for (int kc = 0; kc < 4; ++kc) {
        int c = kc * 32 + lq * 8;
        bfrag8 af[4];
#pragma unroll
        for (int mt = 0; mt < 4; ++mt)
            af[mt] = *(const bfrag8*)(const void*)&s_x[(size_t)(mt * 16 + lm) * 136 + c];
        const unsigned short* sb = sfrag + ((size_t)(kc * 16) + w * 4) * 512 + lane * 8;
#pragma unroll
        for (int nt = 0; nt < 4; ++nt) {
            bfrag8 bf = *(const bfrag8*)(const void*)(sb + (size_t)nt * 512);
#pragma unroll
            for (int mt = 0; mt < 4; ++mt)
                acc[mt][nt] = __builtin_amdgcn_mfma_f32_16x16x32_bf16(
                    af[mt], bf, acc[mt][nt], 0, 0, 0);
        }
    }

    // ---- transpose epilogue ----
    int row_r = tid >> 4;
    int cb = tid & 15;
    float bs[16], bq[16];
#pragma unroll
    for (int k = 0; k < 16; ++k) { bs[k] = 0.f; bq[k] = 0.f; }

#pragma unroll
    for (int chunk = 0; chunk < 4; ++chunk) {
        __syncthreads();
#pragma unroll
        for (int nt = 0; nt < 4; ++nt) {
            int cbw = (w * 4 + nt) * 20;
#pragma unroll
            for (int r = 0; r < 4; ++r)
                s_n[(lq * 4 + r) * 324 + cbw + lm] = acc[chunk][nt][r];
        }
        __syncthreads();
        int tkn = t0 + chunk * 16 + row_r;
        float inv = 1.f / (den1[tkn] + EPS);
        float* tp = tok + (size_t)tkn * COUT + cb * 16;
        const float* np = s_n + row_r * 324 + cb * 20;
        float4 g0 = ((const float4*)tp)[0];
        float4 g1 = ((const float4*)tp)[1];
        float4 g2 = ((const float4*)tp)[2];
        float4 g3 = ((const float4*)tp)[3];
        float4 l0 = ((const float4*)np)[0];
        float4 l1 = ((const float4*)np)[1];
        float4 l2 = ((const float4*)np)[2];
        float4 l3 = ((const float4*)np)[3];
#define RMW4(G, L, K)                                                       \
        {                                                                   \
            float v0 = fmaf(G.x, inv, L.x), v1 = fmaf(G.y, inv, L.y);       \
            float v2 = fmaf(G.z, inv, L.z), v3 = fmaf(G.w, inv, L.w);       \
            G.x = v0; G.y = v1; G.z = v2; G.w = v3;                         \
            bs[K+0] += v0; bq[K+0] = fmaf(v0, v0, bq[K+0]);                 \
            bs[K+1] += v1; bq[K+1] = fmaf(v1, v1, bq[K+1]);                 \
            bs[K+2] += v2; bq[K+2] = fmaf(v2, v2, bq[K+2]);                 \
            bs[K+3] += v3; bq[K+3] = fmaf(v3, v3, bq[K+3]);                 \
        }
        RMW4(g0, l0, 0)
        RMW4(g1, l1, 4)
        RMW4(g2, l2, 8)
        RMW4(g3, l3, 12)
#undef RMW4
        ((float4*)tp)[0] = g0;
        ((float4*)tp)[1] = g1;
        ((float4*)tp)[2] = g2;
        ((float4*)tp)[3] = g3;
    }

    // ---- BN reduction ----
#pragma unroll
    for (int k = 0; k < 16; ++k) {
        bs[k] += __shfl_xor(bs[k], 16, 64);
        bs[k] += __shfl_xor(bs[k], 32, 64);
        bq[k] += __shfl_xor(bq[k], 16, 64);
        bq[k] += __shfl_xor(bq[k], 32, 64);
    }
    __syncthreads();
    if (lq == 0) {
#pragma unroll
        for (int k = 0; k < 16; ++k) {
            s_n[w * 512 + lm * 16 + k] = bs[k];
            s_n[w * 512 + 256 + lm * 16 + k] = bq[k];
        }
    }
    __syncthreads();
    {
        int c = tid;
        float ts = s_n[c] + s_n[512 + c] + s_n[1024 + c] + s_n[1536 + c];
        float tq = s_n[256 + c] + s_n[768 + c] + s_n[1280 + c] + s_n[1792 + c];
        atomicAdd(bnsum + c, ts);
        atomicAdd(bnsq + c, tq);
    }
}

// per-channel BN affine: a=gamma/sqrt(var+eps), bb=beta-mu*a; fold conf head
__global__ void k_bnparams(const float* __restrict__ bnsum, const float* __restrict__ bnsq,
                           const float* __restrict__ gamma, const float* __restrict__ beta,
                           const float* __restrict__ confw, const float* __restrict__ confb,
                           float* __restrict__ abuf, float* __restrict__ bbuf,
                           float* __restrict__ cwa, float* __restrict__ c0) {
    int k = threadIdx.x;
    const float cntv = (float)(BB * NTOK);
    float mu = bnsum[k] / cntv;
    float var = bnsq[k] / cntv - mu * mu;
    float a = gamma[k] * rsqrtf(var + BNEPS);
    float bbv = beta[k] - mu * a;
    abuf[k] = a;
    bbuf[k] = bbv;
    float cw = confw[k];
    cwa[k] = a * cw;
    __shared__ float red[256];
    red[k] = bbv * cw;
    __syncthreads();
    for (int s = 128; s > 0; s >>= 1) {
        if (k < s) red[k] += red[k + s];
        __syncthreads();
    }
    if (k == 0) c0[0] = red[0] + confb[0];
}

// conf = dot(tok, cwa) + c0; emit tokn bf16 (tokb), exp(conf) (wexp),
// and fused relu(tokn) write-back into tok (nt: terminal output, never re-read)
__global__ void k_conf(float* __restrict__ tok, const float* __restrict__ cwa,
                       const float* __restrict__ c0v, const float* __restrict__ abuf,
                       const float* __restrict__ bbuf, float* __restrict__ conf_out,
                       unsigned short* __restrict__ tokb, float* __restrict__ wexp) {
    int tid = threadIdx.x;
    int tkn = blockIdx.x * 16 + (tid >> 4);
    int kc = (tid & 15) * 16;
    float* row = tok + (size_t)tkn * COUT + kc;
    unsigned short* tb = tokb + (size_t)tkn * COUT + kc;
    float s = 0.f;
#pragma unroll
    for (int i = 0; i < 16; i += 4) {
        float4 v = *(const float4*)(row + i);
        float4 w = *(const float4*)(cwa + kc + i);
        float4 a = *(const float4*)(abuf + kc + i);
        float4 bb = *(const float4*)(bbuf + kc + i);
        s += v.x * w.x + v.y * w.y + v.z * w.z + v.w * w.w;
        float t0 = fmaf(a.x, v.x, bb.x);
        float t1 = fmaf(a.y, v.y, bb.y);
        float t2 = fmaf(a.z, v.z, bb.z);
        float t3 = fmaf(a.w, v.w, bb.w);
        ushort4 o;
        o.x = f2bf(t0); o.y = f2bf(t1); o.z = f2bf(t2); o.w = f2bf(t3);
        *(ushort4*)(tb + i) = o;
        nts4(row + i, fmaxf(t0, 0.f), fmaxf(t1, 0.f), fmaxf(t2, 0.f), fmaxf(t3, 0.f));
    }
    for (int off = 8; off > 0; off >>= 1) s += __shfl_down(s, off, 16);
    if ((tid & 15) == 0) {
        float cv = s + c0v[0];
        conf_out[tkn] = cv;
        wexp[tkn] = expf(cv);
    }
}

// cluster as gather over bf16 tokn rows + precomputed exp weights; fused relu epilogue.
// half-wave parallel + depth-1 row pipeline; nt xdown store (terminal output).
__global__ __launch_bounds__(256) void k_gather_cluster(const unsigned short* __restrict__ tokb,
                                                        const float* __restrict__ wexp,
                                                        const int* __restrict__ starts,
                                                        const int* __restrict__ blkexcl,
                                                        const int* __restrict__ cnts,
                                                        const int* __restrict__ pidx,
                                                        float* __restrict__ xdown,
                                                        float* __restrict__ den2) {
    int wv = threadIdx.x >> 6, lane = threadIdx.x & 63;
    int tl = blockIdx.x * 4 + wv;                        // over BB*NS
    int b = tl >> 12;
    int tgt = SEG_64 + tl;
    int start = starts[tgt] + blkexcl[tgt >> 10];
    int cnt = cnts[tgt];
    int half = lane >> 5;
    int ch = (lane & 31) * 8;
    const unsigned short* tb = tokb + (size_t)b * NTOK * COUT + ch;
    const float* we = wexp + (size_t)b * NTOK;
    float num[8];
#pragma unroll
    for (int k = 0; k < 8; ++k) num[k] = 0.f;
    float den = 0.f;
    if (cnt > 0) {
        int last = cnt - 1;
        int jc = half;
        int iac = pidx[start + min(jc, last)];
        float wc = (jc <= last) ? we[iac] : 0.f;
        int jn = 2 + half;
        int ian = pidx[start + min(jn, last)];
        float wn = (jn <= last) ? we[ian] : 0.f;
        const unsigned short* rpn = tb + (size_t)ian * COUT;
        uint4 u = *(const uint4*)(tb + (size_t)iac * COUT);
        for (int j2 = 0; j2 < cnt; j2 += 2) {
            uint4 un = *(const uint4*)rpn;         // next pair's row (dummy at tail)
            int j3 = j2 + 4 + half;
            int ia3 = pidx[start + min(j3, last)];
            float w3 = (j3 <= last) ? we[ia3] : 0.f;
            const unsigned short* rp3 = tb + (size_t)ia3 * COUT;
            ACC8(u, wc)
            den += wc;
            u = un; wc = wn;
            rpn = rp3; wn = w3;
        }
    }
#pragma unroll
    for (int k = 0; k < 8; ++k) num[k] += __shfl_xor(num[k], 32, 64);
    den += __shfl_xor(den, 32, 64);
    if (half == 0) {
        float inv = 1.f / (den + EPS);
        float* o = xdown + (size_t)tl * COUT + ch;
        nts4(o, fmaxf(num[0] * inv, 0.f), fmaxf(num[1] * inv, 0.f),
                fmaxf(num[2] * inv, 0.f), fmaxf(num[3] * inv, 0.f));
        nts4(o + 4, fmaxf(num[4] * inv, 0.f), fmaxf(num[5] * inv, 0.f),
                    fmaxf(num[6] * inv, 0.f), fmaxf(num[7] * inv, 0.f));
        if (lane == 0) den2[tl] = den;
    }
}

// agg_weight_down numerator + per-batch max (positive floats -> uint atomicMax)
__global__ void k_awd1(const float* __restrict__ wexp, const float* __restrict__ den2,
                       const int* __restrict__ idx_agg, const int* __restrict__ cell64,
                       const float* __restrict__ aggw, float* __restrict__ awdt,
                       float* __restrict__ idx_out_f, unsigned int* __restrict__ maxw) {
    int b = blockIdx.x >> 6;
    int chunk = blockIdx.x & 63;
    int base = b * NP + chunk * 1024;
    float lmax = 0.f;
    for (int t = threadIdx.x; t < 1024; t += 256) {
        int gp = base + t;
        int ia = idx_agg[gp];
        int cell = cell64[gp];
        float w = wexp[(size_t)b * NTOK + ia];
        float wt = w / (den2[(size_t)b * NS + cell] + EPS);
        float tv = aggw[gp] * wt;
        awdt[gp] = tv;
        __builtin_nontemporal_store((float)cell, idx_out_f + gp);
        lmax = fmaxf(lmax, tv);
    }
    __shared__ float red[256];
    red[threadIdx.x] = lmax;
    __syncthreads();
    for (int s = 128; s > 0; s >>= 1) {
        if (threadIdx.x < s) red[threadIdx.x] = fmaxf(red[threadIdx.x], red[threadIdx.x + s]);
        __syncthreads();
    }
    if (threadIdx.x == 0) atomicMax(maxw + b, __float_as_uint(red[0]));
}

__global__ void k_awd2(const float* __restrict__ awdt, const unsigned int* __restrict__ maxw,
                       float* __restrict__ awd_out) {
    int i = blockIdx.x * 256 + threadIdx.x;  // over BB*NP
    int b = i >> 16;
    __builtin_nontemporal_store(awdt[i] / __uint_as_float(maxw[b]), awd_out + i);
}

extern "C" void kernel_launch(void* const* d_in, const int* in_sizes, int n_in,
                              void* d_out, int out_size, void* d_ws, size_t ws_size,
                              hipStream_t stream) {
    const float* x        = (const float*)d_in[0];
    const float* loc      = (const float*)d_in[1];
    const int*   idx_agg  = (const int*)d_in[2];
    const float* aggw     = (const float*)d_in[3];
    const float* conv_w   = (const float*)d_in[4];
    const float* conv_b   = (const float*)d_in[5];
    const float* skip_w   = (const float*)d_in[6];
    const float* bn_gamma = (const float*)d_in[7];
    const float* bn_beta  = (const float*)d_in[8];
    const float* conf_w   = (const float*)d_in[9];
    const float* conf_b   = (const float*)d_in[10];

    float* ws      = (float*)d_ws;
    float* bnsum   = ws + BNSUM_OFF;
    float* bnsq    = ws + BNSQ_OFF;
    unsigned int* maxw = (unsigned int*)(ws + MAXW_OFF);
    int*   cnts    = (int*)(ws + CNTS_OFF);
    int*   curs    = (int*)(ws + CURS_OFF);
    unsigned short* ybuf  = (unsigned short*)(ws + YBUF_OFF);
    unsigned short* xmapn = (unsigned short*)(ws + XMAPN_OFF);
    unsigned short* xbf   = (unsigned short*)(ws + XBF_OFF);
    unsigned short* tokb  = (unsigned short*)(ws + TOKB_OFF);
    unsigned short* wfrag = (unsigned short*)(ws + WFRAG_OFF);
    unsigned short* sfrag = (unsigned short*)(ws + SFRAG_OFF);
    float* wexp    = ws + WEXP_OFF;
    float* awdt    = ws + AWDT_OFF;
    float* abuf    = ws + ABUF_OFF;
    float* bbuf    = ws + BBUF_OFF;
    float* cwa     = ws + CWA_OFF;
    float* c0      = ws + C0_OFF;
    int*   cell256 = (int*)(ws + CELL256_OFF);
    int*   cell64  = (int*)(ws + CELL64_OFF);
    float* den1    = ws + DEN1_OFF;
    float* den2    = ws + DEN2_OFF;
    int*   starts  = (int*)(ws + STARTS_OFF);
    int*   blksum  = (int*)(ws + BLKSUM_OFF);
    int*   blkexcl = (int*)(ws + BLKEXCL_OFF);
    int*   pidx    = (int*)(ws + PIDX_OFF);
    int4*  poff    = (int4*)(ws + POFF_OFF);
    float4* pwr    = (float4*)(ws + PW_OFF);

    float* out       = (float*)d_out;
    float* out_xdown = out;                                    // [4,4096,256]
    float* out_x     = out + (size_t)BB * NS * COUT;           // [4,16384,256] (num -> tok -> relu(tokn))
    float* out_conf  = out_x + (size_t)BB * NTOK * COUT;       // [4,16384,1]
    float* out_awd   = out_conf + (size_t)BB * NTOK;           // [4,65536,1]
    float* out_idx   = out_awd + (size_t)BB * NP;              // [4,65536] written as float

    // zero the small accumulator region (ws is poisoned 0xAA every call)
    hipMemsetAsync(d_ws, 0, ZERO_FLOATS * sizeof(float), stream);

    k_prep<<<BB * NP / 256, 256, 0, stream>>>(loc, aggw, cell256, cell64, poff, pwr);
    k_xcast<<<BB * NTOK * CIN / 4 / 256, 256, 0, stream>>>(x, xbf);
    k_wfrag<<<9 * 4 * 16 * 512 / 256, 256, 0, stream>>>(conv_w, wfrag);
    k_sfrag<<<4 * 16 * 512 / 256, 256, 0, stream>>>(skip_w, sfrag);
    k_hist<<<BB * NP / 256, 256, 0, stream>>>(cell256, idx_agg, cell64, cnts);
    k_scan1<<<NSEG / 1024, 256, 0, stream>>>(cnts, starts, blksum);
    k_scan2<<<1, 512, 0, stream>>>(blksum, blkexcl);
    k_fill<<<BB * NP / 256, 256, 0, stream>>>(cell256, idx_agg, cell64, starts,
                                              blkexcl, curs, pidx);
    k_gather_map<<<BB * NP / 8, 256, 0, stream>>>(xbf, starts, blkexcl, cnts, pidx, xmapn);
    k_convmf<<<BB * HD * 2, 256, 0, stream>>>(xmapn, wfrag, conv_b, ybuf);
    k_gather_tok<<<BB * NTOK / 4, 256, 0, stream>>>(ybuf, poff, pwr, starts, blkexcl,
                                                    cnts, pidx, out_x, den1);
    k_tokmf<<<BB * NTOK / 64, 256, 0, stream>>>(xbf, sfrag, den1, out_x, bnsum, bnsq);
    k_bnparams<<<1, 256, 0, stream>>>(bnsum, bnsq, bn_gamma, bn_beta, conf_w, conf_b,
                                      abuf, bbuf, cwa, c0);
    k_conf<<<BB * NTOK / 16, 256, 0, stream>>>(out_x, cwa, c0, abuf, bbuf,
                                               out_conf, tokb, wexp);
    k_gather_cluster<<<BB * NS / 4, 256, 0, stream>>>(tokb, wexp, starts, blkexcl,
                                                      cnts, pidx, out_xdown, den2);
    k_awd1<<<BB * 64, 256, 0, stream>>>(wexp, den2, idx_agg, cell64, aggw,
                                        awdt, out_idx, maxw);
    k_awd2<<<BB * NP / 256, 256, 0, stream>>>(awdt, maxw, out_awd);
}